// Round 14
// baseline (543.587 us; speedup 1.0000x reference)
//
#include <hip/hip_runtime.h>
#include <hip/hip_bf16.h>

#define BATCH 256
#define SEQ   515
#define DIM   512
#define SOUT  512            // SEQ - 4 + 1
#define BS_   (BATCH*SEQ)    // 131840

#define BM 128
#define BK 64
#define NT 5                 // fallback tiling only

typedef float  f32x4  __attribute__((ext_vector_type(4)));
typedef __bf16 bf16x8 __attribute__((ext_vector_type(8)));

__device__ inline unsigned int pack2(float a, float b) {
  unsigned short ua = __builtin_bit_cast(unsigned short, (__bf16)a);
  unsigned short ub = __builtin_bit_cast(unsigned short, (__bf16)b);
  return (unsigned int)ua | ((unsigned int)ub << 16);
}

__device__ inline void gload_lds16(const void* g, void* l) {
  __builtin_amdgcn_global_load_lds(
      (const __attribute__((address_space(1))) unsigned int*)g,
      (__attribute__((address_space(3))) unsigned int*)l, 16, 0, 0);
}

__device__ inline float fastA(float sq) {   // 1/(1+sqrt(max(sq,0))), ~1ulp
  float t = __builtin_amdgcn_sqrtf(fmaxf(sq, 0.f));
  return __builtin_amdgcn_rcpf(1.f + t);
}

// ---------------- fused fp32->bf16 convert + row norms (R13-validated)
__global__ __launch_bounds__(256) void convert_norms_kernel(
    const float* __restrict__ x1, const float* __restrict__ x2,
    unsigned short* __restrict__ x1b, unsigned short* __restrict__ x2b,
    float* __restrict__ nrm) {
  int wid  = blockIdx.x * 4 + (threadIdx.x >> 6);
  int lane = threadIdx.x & 63;
  if (wid >= 2 * BS_) return;
  bool second = wid >= BS_;
  int r = second ? wid - BS_ : wid;
  const float4* p = (const float4*)((second ? x2 : x1) + (size_t)r * DIM) + lane * 2;
  float4 a = p[0];
  float4 b = p[1];
  uint4 wv;
  wv.x = pack2(a.x, a.y); wv.y = pack2(a.z, a.w);
  wv.z = pack2(b.x, b.y); wv.w = pack2(b.z, b.w);
  *((uint4*)((second ? x2b : x1b) + (size_t)r * DIM) + lane) = wv;
  float s = a.x*a.x + a.y*a.y + a.z*a.z + a.w*a.w
          + b.x*b.x + b.y*b.y + b.z*b.z + b.w*b.w;
#pragma unroll
  for (int m = 1; m < 64; m <<= 1) s += __shfl_xor(s, m, 64);
  if (lane == 0) nrm[wid] = s;
}

// ---------------- per-batch distance-GEMM + fused tails + FUSED POOLING.
// R13-validated gemm/tail structure; after the K-loop, the same block pools
// both sides of its batch directly from LDS v-accumulators (no v round-trip,
// no separate pool launch; x reads partially L2-hot).
__global__ __launch_bounds__(512, 2) void gemm_batch_kernel(
    const unsigned short* __restrict__ xab, const unsigned short* __restrict__ xbb,
    const float* __restrict__ nrm, float* __restrict__ out) {
  const int b    = blockIdx.x;
  const int tid  = threadIdx.x;
  const int lane = tid & 63, w = tid >> 6;   // w: 0..7
  const int wr   = w >> 2, wc = w & 3;       // wave grid 2x4 over 256x256

  __shared__ alignas(16) unsigned char As[2][256 * 128];   // 64 KB
  __shared__ alignas(16) unsigned char Bs[2][256 * 128];   // 64 KB
  __shared__ float v1acc[512];
  __shared__ float v2acc[512];
  __shared__ float nals[512];
  __shared__ float nbls[512];
  __shared__ alignas(16) unsigned short t1ls[4][512];      // x1 tails, row3=0
  __shared__ alignas(16) unsigned short t2ls[4][512];      // x2 tails, row3=0
  __shared__ float nt1s[4], nt2s[4], t1sum[4], t2sum[4];

  const char* aB = (const char*)(xab + (size_t)b * SEQ * DIM);
  const char* bB = (const char*)(xbb + (size_t)b * SEQ * DIM);

  v1acc[tid] = 0.f;
  v2acc[tid] = 0.f;
  nals[tid] = nrm[b * SEQ + tid];
  nbls[tid] = nrm[BS_ + b * SEQ + tid];
  {
    int rr = tid >> 7;              // 0..3
    int cc = (tid & 127) * 4;       // 4 bf16 each
    uint2 d1 = {0u, 0u}, d2 = {0u, 0u};
    if (rr < 3) {
      d1 = *(const uint2*)(aB + (size_t)(512 + rr) * 1024 + cc * 2);
      d2 = *(const uint2*)(bB + (size_t)(512 + rr) * 1024 + cc * 2);
    }
    *(uint2*)&t1ls[rr][cc] = d1;
    *(uint2*)&t2ls[rr][cc] = d2;
  }
  if (tid < 3) {
    nt1s[tid] = nrm[b * SEQ + 512 + tid];
    nt2s[tid] = nrm[BS_ + b * SEQ + 512 + tid];
    t1sum[tid] = 0.f; t2sum[tid] = 0.f;
  }

  const int l3       = lane >> 3;
  const int laneByte = ((lane & 7) ^ l3) * 16;

  const int arow = wr * 128 + (lane & 15);
  const int brow = wc * 64  + (lane & 15);

  const char* t1base = (const char*)t1ls + (lane & 3) * 1024;
  const char* t2base = (const char*)t2ls + (lane & 3) * 1024;

  f32x4 acc[8][4] = {};
  f32x4 acc_t1[4] = {};
  f32x4 acc_t2[8] = {};
  f32x4 acc_t3 = {};

  auto STAGE = [&](int s, unsigned char* pa, unsigned char* pb) {
    const int t = s >> 3;
    const int tiN = t >> 1, tjN = (t & 1) ^ (t >> 1), ktN = (s & 7) * BK;
#pragma unroll
    for (int i = 0; i < 4; ++i) {
      int u = w * 4 + i;
      gload_lds16(aB + (size_t)(tiN * 256 + u * 8 + l3) * 1024 + ktN * 2 + laneByte,
                  pa + u * 1024);
      gload_lds16(bB + (size_t)(tjN * 256 + u * 8 + l3) * 1024 + ktN * 2 + laneByte,
                  pb + u * 1024);
    }
  };

  STAGE(0, As[0], Bs[0]);

#pragma unroll 1
  for (int s = 0; s < 32; ++s) {
    asm volatile("s_waitcnt vmcnt(0)" ::: "memory");
    __builtin_amdgcn_s_barrier();
    if (s < 31) STAGE(s + 1, As[(s + 1) & 1], Bs[(s + 1) & 1]);

    const int t  = s >> 3;
    const int ti = t >> 1, tj = (t & 1) ^ (t >> 1);
    const bool gT1 = (wr == 0) && (ti == 0);
    const bool gT2 = (wc == 0) && (tj == 0);
    const bool gT3 = (w == 0) && (t == 0);

    const unsigned char* Ac = As[s & 1];
    const unsigned char* Bc = Bs[s & 1];
#pragma unroll
    for (int ks = 0; ks < 2; ++ks) {
      const int xorterm = ((ks * 4 + (lane >> 4)) ^ (lane & 7)) * 16;
      const int koff = ((s & 7) * 64 + ks * 32 + ((lane >> 4) << 3)) * 2;
      bf16x8 t1f = {}, t2f = {};
      if (gT1 || gT3) t1f = *(const bf16x8*)(t1base + koff);
      if (gT2 || gT3) t2f = *(const bf16x8*)(t2base + koff);
      bf16x8 bfv[4];
#pragma unroll
      for (int f = 0; f < 4; ++f)
        bfv[f] = *(const bf16x8*)(Bc + (brow + f * 16) * 128 + xorterm);
      if (gT1) {
#pragma unroll
        for (int f = 0; f < 4; ++f)
          acc_t1[f] = __builtin_amdgcn_mfma_f32_16x16x32_bf16(t1f, bfv[f], acc_t1[f], 0, 0, 0);
      }
      if (gT3)
        acc_t3 = __builtin_amdgcn_mfma_f32_16x16x32_bf16(t1f, t2f, acc_t3, 0, 0, 0);
#pragma unroll
      for (int fi = 0; fi < 8; ++fi) {
        bf16x8 af = *(const bf16x8*)(Ac + (arow + fi * 16) * 128 + xorterm);
#pragma unroll
        for (int fj = 0; fj < 4; ++fj)
          acc[fi][fj] = __builtin_amdgcn_mfma_f32_16x16x32_bf16(
              af, bfv[fj], acc[fi][fj], 0, 0, 0);
        if (gT2)
          acc_t2[fi] = __builtin_amdgcn_mfma_f32_16x16x32_bf16(af, t2f, acc_t2[fi], 0, 0, 0);
      }
    }

    if ((s & 7) == 7) {                 // tile finished: fused epilogues
      const int ibase = ti * 256 + wr * 128;
      const int jbase = tj * 256 + wc * 64;

      float cs[4] = {0.f, 0.f, 0.f, 0.f};
      int   gj[4]; float nbv[4];
#pragma unroll
      for (int fj = 0; fj < 4; ++fj) {
        gj[fj]  = jbase + fj * 16 + (lane & 15);
        nbv[fj] = nbls[gj[fj]];
      }
#pragma unroll
      for (int fi = 0; fi < 8; ++fi) {
        int r0 = ibase + fi * 16 + ((lane >> 4) << 2);
#pragma unroll
        for (int reg = 0; reg < 4; ++reg) {
          float nav = nals[r0 + reg];
          float sps = 0.f;
#pragma unroll
          for (int fj = 0; fj < 4; ++fj) {
            float Aij = fastA(nav + nbv[fj] - 2.f * acc[fi][fj][reg]);
            sps += Aij;
            cs[fj] += Aij;
          }
          sps += __shfl_xor(sps, 1);  sps += __shfl_xor(sps, 2);
          sps += __shfl_xor(sps, 4);  sps += __shfl_xor(sps, 8);
          if ((lane & 15) == 0) atomicAdd(&v1acc[r0 + reg], sps);
        }
      }
#pragma unroll
      for (int fj = 0; fj < 4; ++fj) {
        float sv = cs[fj];
        sv += __shfl_xor(sv, 16); sv += __shfl_xor(sv, 32);
        if (lane < 16) atomicAdd(&v2acc[gj[fj]], sv);
      }
#pragma unroll
      for (int fi = 0; fi < 8; ++fi)
#pragma unroll
        for (int fj = 0; fj < 4; ++fj)
          acc[fi][fj] = (f32x4){0.f, 0.f, 0.f, 0.f};

      if (gT1) {
        float p0 = 0.f, p1 = 0.f, p2 = 0.f;
#pragma unroll
        for (int f = 0; f < 4; ++f) {
          if (lane < 16) {
            int j = jbase + f * 16 + lane;
            float A0 = fastA(nt1s[0] + nbls[j] - 2.f * acc_t1[f][0]);
            float A1 = fastA(nt1s[1] + nbls[j] - 2.f * acc_t1[f][1]);
            float A2 = fastA(nt1s[2] + nbls[j] - 2.f * acc_t1[f][2]);
            atomicAdd(&v2acc[j], A0 + A1 + A2);
            p0 += A0; p1 += A1; p2 += A2;
          }
          acc_t1[f] = (f32x4){0.f, 0.f, 0.f, 0.f};
        }
        p0 += __shfl_xor(p0, 1); p0 += __shfl_xor(p0, 2);
        p0 += __shfl_xor(p0, 4); p0 += __shfl_xor(p0, 8);
        p1 += __shfl_xor(p1, 1); p1 += __shfl_xor(p1, 2);
        p1 += __shfl_xor(p1, 4); p1 += __shfl_xor(p1, 8);
        p2 += __shfl_xor(p2, 1); p2 += __shfl_xor(p2, 2);
        p2 += __shfl_xor(p2, 4); p2 += __shfl_xor(p2, 8);
        if (lane == 0) {
          atomicAdd(&t1sum[0], p0);
          atomicAdd(&t1sum[1], p1);
          atomicAdd(&t1sum[2], p2);
        }
      }

      if (gT2) {
        float q = 0.f;
        const int colv = lane & 15;
        float ntc = (colv < 3) ? nt2s[colv] : 0.f;
#pragma unroll
        for (int fi = 0; fi < 8; ++fi) {
          if (colv < 3) {
            int i0 = ibase + fi * 16 + ((lane >> 4) << 2);
#pragma unroll
            for (int e = 0; e < 4; ++e) {
              float Av = fastA(ntc + nals[i0 + e] - 2.f * acc_t2[fi][e]);
              atomicAdd(&v1acc[i0 + e], Av);
              q += Av;
            }
          }
          acc_t2[fi] = (f32x4){0.f, 0.f, 0.f, 0.f};
        }
        q += __shfl_xor(q, 16); q += __shfl_xor(q, 32);
        if (lane < 3) atomicAdd(&t2sum[lane], q);
      }

      if (gT3) {
        if (lane < 3) {
#pragma unroll
          for (int e = 0; e < 3; ++e) {
            float Av = fastA(nt1s[e] + nt2s[lane] - 2.f * acc_t3[e]);
            atomicAdd(&t1sum[e], Av);
            atomicAdd(&t2sum[lane], Av);
          }
        }
        acc_t3 = (f32x4){0.f, 0.f, 0.f, 0.f};
      }
    }
  }
  __syncthreads();   // v1acc/v2acc/t1sum/t2sum final

  // ---------- fused width-4 pooling (v straight from LDS)
  const int rg  = tid >> 7;        // 0..3 row group (128 out rows each)
  const int col = tid & 127;       // float4 column
  const int j0  = rg * 128;
#pragma unroll 1
  for (int side = 0; side < 2; ++side) {
    const unsigned short* xb = (side ? xbb : xab) + (size_t)b * SEQ * DIM;
    const float* vsrc = side ? v2acc : v1acc;
    const float* tsrc = side ? t2sum : t1sum;
    float* ob = out + (size_t)side * ((size_t)BATCH * SOUT * DIM)
                    + (size_t)b * SOUT * DIM;
    float4 r0 = {0,0,0,0}, r1 = r0, r2 = r0, r3 = r0;
#pragma unroll 1
    for (int g = 0; g < 33; ++g) {
#pragma unroll
      for (int u = 0; u < 4; ++u) {
        int kk = g * 4 + u;          // 0..131 (131 used; 132nd guarded off)
        int k  = j0 + kk;
        float4 val = {0,0,0,0};
        if (kk < 131 && k < SEQ) {
          float w = (k < 512) ? vsrc[k] : tsrc[k - 512];
          uint2 xv = *(const uint2*)(xb + (size_t)k * DIM + col * 4);
          val.x = w * __builtin_bit_cast(float, xv.x << 16);
          val.y = w * __builtin_bit_cast(float, xv.x & 0xffff0000u);
          val.z = w * __builtin_bit_cast(float, xv.y << 16);
          val.w = w * __builtin_bit_cast(float, xv.y & 0xffff0000u);
        }
        if      (u == 0) r0 = val;
        else if (u == 1) r1 = val;
        else if (u == 2) r2 = val;
        else             r3 = val;
        if (kk >= 3 && kk <= 130) {
          int j = k - 3;             // j0 .. j0+127
          float4 sum;
          sum.x = r0.x + r1.x + r2.x + r3.x;
          sum.y = r0.y + r1.y + r2.y + r3.y;
          sum.z = r0.z + r1.z + r2.z + r3.z;
          sum.w = r0.w + r1.w + r2.w + r3.w;
          *(float4*)(ob + (size_t)j * DIM + col * 4) = sum;
        }
      }
    }
  }
}

// ---------------- fallback (round-1, validated): norms + fused fp32 GEMM
__global__ __launch_bounds__(256) void norms_kernel(
    const float* __restrict__ x1, const float* __restrict__ x2,
    float* __restrict__ nrm) {
  int wid  = blockIdx.x * 4 + (threadIdx.x >> 6);
  int lane = threadIdx.x & 63;
  if (wid >= 2 * BS_) return;
  const float* base = (wid < BS_) ? x1 : x2;
  int r = (wid < BS_) ? wid : wid - BS_;
  const float4* p = (const float4*)(base + (size_t)r * DIM);
  float4 a = p[lane];
  float4 b = p[lane + 64];
  float s = a.x*a.x + a.y*a.y + a.z*a.z + a.w*a.w
          + b.x*b.x + b.y*b.y + b.z*b.z + b.w*b.w;
#pragma unroll
  for (int m = 1; m < 64; m <<= 1) s += __shfl_xor(s, m, 64);
  if (lane == 0) nrm[wid] = s;
}

__global__ __launch_bounds__(256) void attn_sums_kernel(
    const float* __restrict__ x1, const float* __restrict__ x2,
    const float* __restrict__ nrm,
    float* __restrict__ v1, float* __restrict__ v2) {
  const int b   = blockIdx.y;
  const int ti  = blockIdx.x / NT, tj = blockIdx.x % NT;
  const int tid = threadIdx.x;
  const int lane = tid & 63, wid = tid >> 6;
  const int wr = wid >> 1, wc = wid & 1;

  __shared__ alignas(16) unsigned char AsB[BM * BK * 2];
  __shared__ alignas(16) unsigned char BsB[BM * BK * 2];

  const float* aB = x1 + (size_t)b * SEQ * DIM;
  const float* bB = x2 + (size_t)b * SEQ * DIM;

  f32x4 acc[4][4] = {};
  const int rloc = tid >> 4;
  const int c4   = tid & 15;

  for (int kt = 0; kt < DIM; kt += BK) {
#pragma unroll
    for (int p = 0; p < 8; ++p) {
      int r = p * 16 + rloc;
      int wroff = r * 128 + ((c4 * 8) ^ ((r & 7) << 4));
      int gra = ti * BM + r;
      float4 va = make_float4(0.f, 0.f, 0.f, 0.f);
      if (gra < SEQ) va = *(const float4*)(aB + (size_t)gra * DIM + kt + c4 * 4);
      uint2 wa; wa.x = pack2(va.x, va.y); wa.y = pack2(va.z, va.w);
      *(uint2*)(AsB + wroff) = wa;
      int grb = tj * BM + r;
      float4 vb = make_float4(0.f, 0.f, 0.f, 0.f);
      if (grb < SEQ) vb = *(const float4*)(bB + (size_t)grb * DIM + kt + c4 * 4);
      uint2 wb; wb.x = pack2(vb.x, vb.y); wb.y = pack2(vb.z, vb.w);
      *(uint2*)(BsB + wroff) = wb;
    }
    __syncthreads();
#pragma unroll
    for (int ks = 0; ks < 2; ++ks) {
      bf16x8 af[4], bfv[4];
      int kb = ks * 64 + ((lane >> 4) << 4);
#pragma unroll
      for (int f = 0; f < 4; ++f) {
        int ar = wr * 64 + f * 16 + (lane & 15);
        af[f]  = *(const bf16x8*)(AsB + ar * 128 + (kb ^ ((ar & 7) << 4)));
        int br = wc * 64 + f * 16 + (lane & 15);
        bfv[f] = *(const bf16x8*)(BsB + br * 128 + (kb ^ ((br & 7) << 4)));
      }
#pragma unroll
      for (int fi = 0; fi < 4; ++fi)
#pragma unroll
        for (int fj = 0; fj < 4; ++fj)
          acc[fi][fj] = __builtin_amdgcn_mfma_f32_16x16x32_bf16(
              af[fi], bfv[fj], acc[fi][fj], 0, 0, 0);
    }
    __syncthreads();
  }

  const float* na = nrm;
  const float* nb = nrm + BS_;
  const int ibase = ti * BM + wr * 64;
  const int jbase = tj * BM + wc * 64;

  float cs[4] = {0.f, 0.f, 0.f, 0.f};
  int   gj[4]; float nbv[4]; bool jv[4];
#pragma unroll
  for (int fj = 0; fj < 4; ++fj) {
    gj[fj]  = jbase + fj * 16 + (lane & 15);
    jv[fj]  = gj[fj] < SEQ;
    nbv[fj] = jv[fj] ? nb[b * SEQ + gj[fj]] : 0.f;
  }
#pragma unroll
  for (int fi = 0; fi < 4; ++fi) {
    int r0 = ibase + fi * 16 + ((lane >> 4) << 2);
    float rs[4];
#pragma unroll
    for (int reg = 0; reg < 4; ++reg) {
      int gi = r0 + reg;
      bool iv = gi < SEQ;
      float nav = iv ? na[b * SEQ + gi] : 0.f;
      float s = 0.f;
#pragma unroll
      for (int fj = 0; fj < 4; ++fj) {
        float c  = acc[fi][fj][reg];
        float sq = nav + nbv[fj] - 2.f * c;
        float Aij = (iv && jv[fj]) ? 1.f / (1.f + sqrtf(fmaxf(sq, 0.f))) : 0.f;
        s += Aij;
        cs[fj] += Aij;
      }
      rs[reg] = s;
    }
#pragma unroll
    for (int reg = 0; reg < 4; ++reg) {
      float s = rs[reg];
      s += __shfl_xor(s, 1);  s += __shfl_xor(s, 2);
      s += __shfl_xor(s, 4);  s += __shfl_xor(s, 8);
      int gi = r0 + reg;
      if ((lane & 15) == 0 && gi < SEQ) atomicAdd(&v1[b * SEQ + gi], s);
    }
  }
#pragma unroll
  for (int fj = 0; fj < 4; ++fj) {
    float s = cs[fj];
    s += __shfl_xor(s, 16); s += __shfl_xor(s, 32);
    if (lane < 16 && jv[fj]) atomicAdd(&v2[b * SEQ + gj[fj]], s);
  }
}

// ---------------- width-4 pooling, fp32 x input (fallback path)
__global__ __launch_bounds__(128) void pool_kernel(
    const float* __restrict__ x1, const float* __restrict__ x2,
    const float* __restrict__ v1, const float* __restrict__ v2,
    float* __restrict__ out) {
  const int t     = threadIdx.x;
  const int chunk = blockIdx.x;
  const int b     = blockIdx.y;
  const int which = blockIdx.z;
  const float*  x   = which ? x2 : x1;
  const float*  vec = which ? v2 : v1;
  float4* o = (float4*)out + (size_t)which * ((size_t)BATCH * SOUT * DIM / 4);
  const float4* xr = (const float4*)(x + (size_t)b * SEQ * DIM);
  const float*  vb = vec + b * SEQ;
  const int j0 = chunk * 64;

  float4 r0 = {0,0,0,0}, r1 = {0,0,0,0}, r2 = {0,0,0,0}, r3 = {0,0,0,0};
#pragma unroll 1
  for (int g = 0; g < 17; ++g) {
#pragma unroll
    for (int u = 0; u < 4; ++u) {
      int kk = g * 4 + u;
      int k  = j0 + kk;
      float4 val = {0,0,0,0};
      if (k < SEQ) {
        float  w  = vb[k];
        float4 xv = xr[(size_t)k * 128 + t];
        val.x = w * xv.x; val.y = w * xv.y; val.z = w * xv.z; val.w = w * xv.w;
      }
      if      (u == 0) r0 = val;
      else if (u == 1) r1 = val;
      else if (u == 2) r2 = val;
      else             r3 = val;
      if (kk >= 3 && kk <= 66) {
        int jout = k - 3;
        float4 sum;
        sum.x = r0.x + r1.x + r2.x + r3.x;
        sum.y = r0.y + r1.y + r2.y + r3.y;
        sum.z = r0.z + r1.z + r2.z + r3.z;
        sum.w = r0.w + r1.w + r2.w + r3.w;
        o[((size_t)b * SOUT + jout) * 128 + t] = sum;
      }
    }
  }
}

extern "C" void kernel_launch(void* const* d_in, const int* in_sizes, int n_in,
                              void* d_out, int out_size, void* d_ws, size_t ws_size,
                              hipStream_t stream) {
  const float* x1 = (const float*)d_in[0];
  const float* x2 = (const float*)d_in[1];
  float* out = (float*)d_out;
  float* ws  = (float*)d_ws;
  float* nrm = ws;             // 2*BS_ floats (na | nb)
  float* v1  = ws + 2 * BS_;   // BS_ floats (fallback only)
  float* v2  = ws + 3 * BS_;   // BS_ floats (fallback only)

  const size_t need = (size_t)4 * BS_ * sizeof(float)
                    + (size_t)2 * BS_ * DIM * sizeof(unsigned short);

  if (ws_size >= need) {
    unsigned short* x1b = (unsigned short*)(ws + 4 * BS_);
    unsigned short* x2b = x1b + (size_t)BS_ * DIM;
    convert_norms_kernel<<<(2 * BS_ + 3) / 4, 256, 0, stream>>>(x1, x2, x1b, x2b, nrm);
    gemm_batch_kernel<<<BATCH, 512, 0, stream>>>(x1b, x2b, nrm, out);
  } else {
    hipMemsetAsync(v1, 0, 2 * (size_t)BS_ * sizeof(float), stream);
    norms_kernel<<<(2 * BS_ + 3) / 4, 256, 0, stream>>>(x1, x2, nrm);
    attn_sums_kernel<<<dim3(NT * NT, BATCH), 256, 0, stream>>>(x1, x2, nrm, v1, v2);
    pool_kernel<<<dim3(8, BATCH, 2), 128, 0, stream>>>(x1, x2, v1, v2, out);
  }
}

// Round 16
// 430.885 us; speedup vs baseline: 1.2616x; 1.2616x over previous
//
#include <hip/hip_runtime.h>
#include <hip/hip_bf16.h>

#define BATCH 256
#define SEQ   515
#define DIM   512
#define SOUT  512            // SEQ - 4 + 1
#define BS_   (BATCH*SEQ)    // 131840

#define BM 128
#define BK 64
#define NT 5                 // fallback tiling only

typedef float  f32x4  __attribute__((ext_vector_type(4)));
typedef __bf16 bf16x8 __attribute__((ext_vector_type(8)));

__device__ inline unsigned int pack2(float a, float b) {
  unsigned short ua = __builtin_bit_cast(unsigned short, (__bf16)a);
  unsigned short ub = __builtin_bit_cast(unsigned short, (__bf16)b);
  return (unsigned int)ua | ((unsigned int)ub << 16);
}

__device__ inline void gload_lds16(const void* g, void* l) {
  __builtin_amdgcn_global_load_lds(
      (const __attribute__((address_space(1))) unsigned int*)g,
      (__attribute__((address_space(3))) unsigned int*)l, 16, 0, 0);
}

__device__ inline float fastA(float sq) {   // 1/(1+sqrt(max(sq,0))), ~1ulp
  float t = __builtin_amdgcn_sqrtf(fmaxf(sq, 0.f));
  return __builtin_amdgcn_rcpf(1.f + t);
}

// ---------------- fused fp32->bf16 convert + row norms (R13-validated)
__global__ __launch_bounds__(256) void convert_norms_kernel(
    const float* __restrict__ x1, const float* __restrict__ x2,
    unsigned short* __restrict__ x1b, unsigned short* __restrict__ x2b,
    float* __restrict__ nrm) {
  int wid  = blockIdx.x * 4 + (threadIdx.x >> 6);
  int lane = threadIdx.x & 63;
  if (wid >= 2 * BS_) return;
  bool second = wid >= BS_;
  int r = second ? wid - BS_ : wid;
  const float4* p = (const float4*)((second ? x2 : x1) + (size_t)r * DIM) + lane * 2;
  float4 a = p[0];
  float4 b = p[1];
  uint4 wv;
  wv.x = pack2(a.x, a.y); wv.y = pack2(a.z, a.w);
  wv.z = pack2(b.x, b.y); wv.w = pack2(b.z, b.w);
  *((uint4*)((second ? x2b : x1b) + (size_t)r * DIM) + lane) = wv;
  float s = a.x*a.x + a.y*a.y + a.z*a.z + a.w*a.w
          + b.x*b.x + b.y*b.y + b.z*b.z + b.w*b.w;
#pragma unroll
  for (int m = 1; m < 64; m <<= 1) s += __shfl_xor(s, m, 64);
  if (lane == 0) nrm[wid] = s;
}

// ---------------- per-batch distance-GEMM + fused tails (R13-validated)
__global__ __launch_bounds__(512, 2) void gemm_batch_kernel(
    const unsigned short* __restrict__ xab, const unsigned short* __restrict__ xbb,
    const float* __restrict__ nrm,
    float* __restrict__ v1, float* __restrict__ v2) {
  const int b    = blockIdx.x;
  const int tid  = threadIdx.x;
  const int lane = tid & 63, w = tid >> 6;   // w: 0..7
  const int wr   = w >> 2, wc = w & 3;       // wave grid 2x4 over 256x256

  __shared__ alignas(16) unsigned char As[2][256 * 128];   // 64 KB
  __shared__ alignas(16) unsigned char Bs[2][256 * 128];   // 64 KB
  __shared__ float v1acc[512];
  __shared__ float v2acc[512];
  __shared__ float nals[512];
  __shared__ float nbls[512];
  __shared__ alignas(16) unsigned short t1ls[4][512];      // x1 tails, row3=0
  __shared__ alignas(16) unsigned short t2ls[4][512];      // x2 tails, row3=0
  __shared__ float nt1s[4], nt2s[4], t1sum[4], t2sum[4];

  const char* aB = (const char*)(xab + (size_t)b * SEQ * DIM);
  const char* bB = (const char*)(xbb + (size_t)b * SEQ * DIM);

  v1acc[tid] = 0.f;
  v2acc[tid] = 0.f;
  nals[tid] = nrm[b * SEQ + tid];
  nbls[tid] = nrm[BS_ + b * SEQ + tid];
  {
    int rr = tid >> 7;              // 0..3
    int cc = (tid & 127) * 4;       // 4 bf16 each
    uint2 d1 = {0u, 0u}, d2 = {0u, 0u};
    if (rr < 3) {
      d1 = *(const uint2*)(aB + (size_t)(512 + rr) * 1024 + cc * 2);
      d2 = *(const uint2*)(bB + (size_t)(512 + rr) * 1024 + cc * 2);
    }
    *(uint2*)&t1ls[rr][cc] = d1;
    *(uint2*)&t2ls[rr][cc] = d2;
  }
  if (tid < 3) {
    nt1s[tid] = nrm[b * SEQ + 512 + tid];
    nt2s[tid] = nrm[BS_ + b * SEQ + 512 + tid];
    t1sum[tid] = 0.f; t2sum[tid] = 0.f;
  }

  const int l3       = lane >> 3;
  const int laneByte = ((lane & 7) ^ l3) * 16;

  const int arow = wr * 128 + (lane & 15);
  const int brow = wc * 64  + (lane & 15);

  const char* t1base = (const char*)t1ls + (lane & 3) * 1024;
  const char* t2base = (const char*)t2ls + (lane & 3) * 1024;

  f32x4 acc[8][4] = {};
  f32x4 acc_t1[4] = {};
  f32x4 acc_t2[8] = {};
  f32x4 acc_t3 = {};

  auto STAGE = [&](int s, unsigned char* pa, unsigned char* pb) {
    const int t = s >> 3;
    const int tiN = t >> 1, tjN = (t & 1) ^ (t >> 1), ktN = (s & 7) * BK;
#pragma unroll
    for (int i = 0; i < 4; ++i) {
      int u = w * 4 + i;
      gload_lds16(aB + (size_t)(tiN * 256 + u * 8 + l3) * 1024 + ktN * 2 + laneByte,
                  pa + u * 1024);
      gload_lds16(bB + (size_t)(tjN * 256 + u * 8 + l3) * 1024 + ktN * 2 + laneByte,
                  pb + u * 1024);
    }
  };

  STAGE(0, As[0], Bs[0]);

#pragma unroll 1
  for (int s = 0; s < 32; ++s) {
    asm volatile("s_waitcnt vmcnt(0)" ::: "memory");
    __builtin_amdgcn_s_barrier();
    if (s < 31) STAGE(s + 1, As[(s + 1) & 1], Bs[(s + 1) & 1]);

    const int t  = s >> 3;
    const int ti = t >> 1, tj = (t & 1) ^ (t >> 1);
    const bool gT1 = (wr == 0) && (ti == 0);
    const bool gT2 = (wc == 0) && (tj == 0);
    const bool gT3 = (w == 0) && (t == 0);

    const unsigned char* Ac = As[s & 1];
    const unsigned char* Bc = Bs[s & 1];
#pragma unroll
    for (int ks = 0; ks < 2; ++ks) {
      const int xorterm = ((ks * 4 + (lane >> 4)) ^ (lane & 7)) * 16;
      const int koff = ((s & 7) * 64 + ks * 32 + ((lane >> 4) << 3)) * 2;
      bf16x8 t1f = {}, t2f = {};
      if (gT1 || gT3) t1f = *(const bf16x8*)(t1base + koff);
      if (gT2 || gT3) t2f = *(const bf16x8*)(t2base + koff);
      bf16x8 bfv[4];
#pragma unroll
      for (int f = 0; f < 4; ++f)
        bfv[f] = *(const bf16x8*)(Bc + (brow + f * 16) * 128 + xorterm);
      if (gT1) {
#pragma unroll
        for (int f = 0; f < 4; ++f)
          acc_t1[f] = __builtin_amdgcn_mfma_f32_16x16x32_bf16(t1f, bfv[f], acc_t1[f], 0, 0, 0);
      }
      if (gT3)
        acc_t3 = __builtin_amdgcn_mfma_f32_16x16x32_bf16(t1f, t2f, acc_t3, 0, 0, 0);
#pragma unroll
      for (int fi = 0; fi < 8; ++fi) {
        bf16x8 af = *(const bf16x8*)(Ac + (arow + fi * 16) * 128 + xorterm);
#pragma unroll
        for (int fj = 0; fj < 4; ++fj)
          acc[fi][fj] = __builtin_amdgcn_mfma_f32_16x16x32_bf16(
              af, bfv[fj], acc[fi][fj], 0, 0, 0);
        if (gT2)
          acc_t2[fi] = __builtin_amdgcn_mfma_f32_16x16x32_bf16(af, t2f, acc_t2[fi], 0, 0, 0);
      }
    }

    if ((s & 7) == 7) {                 // tile finished: fused epilogues
      const int ibase = ti * 256 + wr * 128;
      const int jbase = tj * 256 + wc * 64;

      float cs[4] = {0.f, 0.f, 0.f, 0.f};
      int   gj[4]; float nbv[4];
#pragma unroll
      for (int fj = 0; fj < 4; ++fj) {
        gj[fj]  = jbase + fj * 16 + (lane & 15);
        nbv[fj] = nbls[gj[fj]];
      }
#pragma unroll
      for (int fi = 0; fi < 8; ++fi) {
        int r0 = ibase + fi * 16 + ((lane >> 4) << 2);
#pragma unroll
        for (int reg = 0; reg < 4; ++reg) {
          float nav = nals[r0 + reg];
          float sps = 0.f;
#pragma unroll
          for (int fj = 0; fj < 4; ++fj) {
            float Aij = fastA(nav + nbv[fj] - 2.f * acc[fi][fj][reg]);
            sps += Aij;
            cs[fj] += Aij;
          }
          sps += __shfl_xor(sps, 1);  sps += __shfl_xor(sps, 2);
          sps += __shfl_xor(sps, 4);  sps += __shfl_xor(sps, 8);
          if ((lane & 15) == 0) atomicAdd(&v1acc[r0 + reg], sps);
        }
      }
#pragma unroll
      for (int fj = 0; fj < 4; ++fj) {
        float sv = cs[fj];
        sv += __shfl_xor(sv, 16); sv += __shfl_xor(sv, 32);
        if (lane < 16) atomicAdd(&v2acc[gj[fj]], sv);
      }
#pragma unroll
      for (int fi = 0; fi < 8; ++fi)
#pragma unroll
        for (int fj = 0; fj < 4; ++fj)
          acc[fi][fj] = (f32x4){0.f, 0.f, 0.f, 0.f};

      if (gT1) {
        float p0 = 0.f, p1 = 0.f, p2 = 0.f;
#pragma unroll
        for (int f = 0; f < 4; ++f) {
          if (lane < 16) {
            int j = jbase + f * 16 + lane;
            float A0 = fastA(nt1s[0] + nbls[j] - 2.f * acc_t1[f][0]);
            float A1 = fastA(nt1s[1] + nbls[j] - 2.f * acc_t1[f][1]);
            float A2 = fastA(nt1s[2] + nbls[j] - 2.f * acc_t1[f][2]);
            atomicAdd(&v2acc[j], A0 + A1 + A2);
            p0 += A0; p1 += A1; p2 += A2;
          }
          acc_t1[f] = (f32x4){0.f, 0.f, 0.f, 0.f};
        }
        p0 += __shfl_xor(p0, 1); p0 += __shfl_xor(p0, 2);
        p0 += __shfl_xor(p0, 4); p0 += __shfl_xor(p0, 8);
        p1 += __shfl_xor(p1, 1); p1 += __shfl_xor(p1, 2);
        p1 += __shfl_xor(p1, 4); p1 += __shfl_xor(p1, 8);
        p2 += __shfl_xor(p2, 1); p2 += __shfl_xor(p2, 2);
        p2 += __shfl_xor(p2, 4); p2 += __shfl_xor(p2, 8);
        if (lane == 0) {
          atomicAdd(&t1sum[0], p0);
          atomicAdd(&t1sum[1], p1);
          atomicAdd(&t1sum[2], p2);
        }
      }

      if (gT2) {
        float q = 0.f;
        const int colv = lane & 15;
        float ntc = (colv < 3) ? nt2s[colv] : 0.f;
#pragma unroll
        for (int fi = 0; fi < 8; ++fi) {
          if (colv < 3) {
            int i0 = ibase + fi * 16 + ((lane >> 4) << 2);
#pragma unroll
            for (int e = 0; e < 4; ++e) {
              float Av = fastA(ntc + nals[i0 + e] - 2.f * acc_t2[fi][e]);
              atomicAdd(&v1acc[i0 + e], Av);
              q += Av;
            }
          }
          acc_t2[fi] = (f32x4){0.f, 0.f, 0.f, 0.f};
        }
        q += __shfl_xor(q, 16); q += __shfl_xor(q, 32);
        if (lane < 3) atomicAdd(&t2sum[lane], q);
      }

      if (gT3) {
        if (lane < 3) {
#pragma unroll
          for (int e = 0; e < 3; ++e) {
            float Av = fastA(nt1s[e] + nt2s[lane] - 2.f * acc_t3[e]);
            atomicAdd(&t1sum[e], Av);
            atomicAdd(&t2sum[lane], Av);
          }
        }
        acc_t3 = (f32x4){0.f, 0.f, 0.f, 0.f};
      }
    }
  }
  __syncthreads();

  v1[b * SEQ + tid] = v1acc[tid];
  v2[b * SEQ + tid] = v2acc[tid];
  if (tid < 3) {
    v1[b * SEQ + 512 + tid] = t1sum[tid];
    v2[b * SEQ + 512 + tid] = t2sum[tid];
  }
}

// ---------------- width-4 pooling, bf16 x input.
// R9-validated structure + (a) unroll 2 so next window's loads hoist above
// current stores (stores share vmcnt with loads -> convoy otherwise),
// (b) nontemporal output stores via ext-vector f32x4 (clang builtin needs a
// true vector type, not HIP's float4 struct).
__global__ __launch_bounds__(128) void pool_bf16_kernel(
    const unsigned short* __restrict__ x1b, const unsigned short* __restrict__ x2b,
    const float* __restrict__ v1, const float* __restrict__ v2,
    float* __restrict__ out) {
  const int t     = threadIdx.x;   // ushort4 column 0..127
  const int chunk = blockIdx.x;    // 0..7  (64 output rows each)
  const int b     = blockIdx.y;
  const int which = blockIdx.z;
  const unsigned short* x = which ? x2b : x1b;
  const float*        vec = which ? v2 : v1;
  f32x4* o = (f32x4*)out + (size_t)which * ((size_t)BATCH * SOUT * DIM / 4);
  const ushort4* xr = (const ushort4*)(x + (size_t)b * SEQ * DIM);
  const float*   vb = vec + b * SEQ;
  const int j0 = chunk * 64;

  f32x4 r0 = {0,0,0,0}, r1 = {0,0,0,0}, r2 = {0,0,0,0}, r3 = {0,0,0,0};
#pragma unroll 2
  for (int g = 0; g < 17; ++g) {
#pragma unroll
    for (int u = 0; u < 4; ++u) {
      int kk = g * 4 + u;          // 0..67
      int k  = j0 + kk;
      f32x4 val = {0,0,0,0};
      if (k < SEQ) {
        float   w  = vb[k];
        ushort4 xv = xr[(size_t)k * 128 + t];
        val[0] = w * (float)__builtin_bit_cast(__bf16, (unsigned short)xv.x);
        val[1] = w * (float)__builtin_bit_cast(__bf16, (unsigned short)xv.y);
        val[2] = w * (float)__builtin_bit_cast(__bf16, (unsigned short)xv.z);
        val[3] = w * (float)__builtin_bit_cast(__bf16, (unsigned short)xv.w);
      }
      if      (u == 0) r0 = val;
      else if (u == 1) r1 = val;
      else if (u == 2) r2 = val;
      else             r3 = val;
      if (kk >= 3 && kk <= 66) {
        int jout = k - 3;
        f32x4 sum = r0 + r1 + r2 + r3;
        __builtin_nontemporal_store(sum, &o[((size_t)b * SOUT + jout) * 128 + t]);
      }
    }
  }
}

// ---------------- fallback (round-1, validated): norms + fused fp32 GEMM
__global__ __launch_bounds__(256) void norms_kernel(
    const float* __restrict__ x1, const float* __restrict__ x2,
    float* __restrict__ nrm) {
  int wid  = blockIdx.x * 4 + (threadIdx.x >> 6);
  int lane = threadIdx.x & 63;
  if (wid >= 2 * BS_) return;
  const float* base = (wid < BS_) ? x1 : x2;
  int r = (wid < BS_) ? wid : wid - BS_;
  const float4* p = (const float4*)(base + (size_t)r * DIM);
  float4 a = p[lane];
  float4 b = p[lane + 64];
  float s = a.x*a.x + a.y*a.y + a.z*a.z + a.w*a.w
          + b.x*b.x + b.y*b.y + b.z*b.z + b.w*b.w;
#pragma unroll
  for (int m = 1; m < 64; m <<= 1) s += __shfl_xor(s, m, 64);
  if (lane == 0) nrm[wid] = s;
}

__global__ __launch_bounds__(256) void attn_sums_kernel(
    const float* __restrict__ x1, const float* __restrict__ x2,
    const float* __restrict__ nrm,
    float* __restrict__ v1, float* __restrict__ v2) {
  const int b   = blockIdx.y;
  const int ti  = blockIdx.x / NT, tj = blockIdx.x % NT;
  const int tid = threadIdx.x;
  const int lane = tid & 63, wid = tid >> 6;
  const int wr = wid >> 1, wc = wid & 1;

  __shared__ alignas(16) unsigned char AsB[BM * BK * 2];
  __shared__ alignas(16) unsigned char BsB[BM * BK * 2];

  const float* aB = x1 + (size_t)b * SEQ * DIM;
  const float* bB = x2 + (size_t)b * SEQ * DIM;

  f32x4 acc[4][4] = {};
  const int rloc = tid >> 4;
  const int c4   = tid & 15;

  for (int kt = 0; kt < DIM; kt += BK) {
#pragma unroll
    for (int p = 0; p < 8; ++p) {
      int r = p * 16 + rloc;
      int wroff = r * 128 + ((c4 * 8) ^ ((r & 7) << 4));
      int gra = ti * BM + r;
      float4 va = make_float4(0.f, 0.f, 0.f, 0.f);
      if (gra < SEQ) va = *(const float4*)(aB + (size_t)gra * DIM + kt + c4 * 4);
      uint2 wa; wa.x = pack2(va.x, va.y); wa.y = pack2(va.z, va.w);
      *(uint2*)(AsB + wroff) = wa;
      int grb = tj * BM + r;
      float4 vb = make_float4(0.f, 0.f, 0.f, 0.f);
      if (grb < SEQ) vb = *(const float4*)(bB + (size_t)grb * DIM + kt + c4 * 4);
      uint2 wb; wb.x = pack2(vb.x, vb.y); wb.y = pack2(vb.z, vb.w);
      *(uint2*)(BsB + wroff) = wb;
    }
    __syncthreads();
#pragma unroll
    for (int ks = 0; ks < 2; ++ks) {
      bf16x8 af[4], bfv[4];
      int kb = ks * 64 + ((lane >> 4) << 4);
#pragma unroll
      for (int f = 0; f < 4; ++f) {
        int ar = wr * 64 + f * 16 + (lane & 15);
        af[f]  = *(const bf16x8*)(AsB + ar * 128 + (kb ^ ((ar & 7) << 4)));
        int br = wc * 64 + f * 16 + (lane & 15);
        bfv[f] = *(const bf16x8*)(BsB + br * 128 + (kb ^ ((br & 7) << 4)));
      }
#pragma unroll
      for (int fi = 0; fi < 4; ++fi)
#pragma unroll
        for (int fj = 0; fj < 4; ++fj)
          acc[fi][fj] = __builtin_amdgcn_mfma_f32_16x16x32_bf16(
              af[fi], bfv[fj], acc[fi][fj], 0, 0, 0);
    }
    __syncthreads();
  }

  const float* na = nrm;
  const float* nb = nrm + BS_;
  const int ibase = ti * BM + wr * 64;
  const int jbase = tj * BM + wc * 64;

  float cs[4] = {0.f, 0.f, 0.f, 0.f};
  int   gj[4]; float nbv[4]; bool jv[4];
#pragma unroll
  for (int fj = 0; fj < 4; ++fj) {
    gj[fj]  = jbase + fj * 16 + (lane & 15);
    jv[fj]  = gj[fj] < SEQ;
    nbv[fj] = jv[fj] ? nb[b * SEQ + gj[fj]] : 0.f;
  }
#pragma unroll
  for (int fi = 0; fi < 4; ++fi) {
    int r0 = ibase + fi * 16 + ((lane >> 4) << 2);
    float rs[4];
#pragma unroll
    for (int reg = 0; reg < 4; ++reg) {
      int gi = r0 + reg;
      bool iv = gi < SEQ;
      float nav = iv ? na[b * SEQ + gi] : 0.f;
      float s = 0.f;
#pragma unroll
      for (int fj = 0; fj < 4; ++fj) {
        float c  = acc[fi][fj][reg];
        float sq = nav + nbv[fj] - 2.f * c;
        float Aij = (iv && jv[fj]) ? 1.f / (1.f + sqrtf(fmaxf(sq, 0.f))) : 0.f;
        s += Aij;
        cs[fj] += Aij;
      }
      rs[reg] = s;
    }
#pragma unroll
    for (int reg = 0; reg < 4; ++reg) {
      float s = rs[reg];
      s += __shfl_xor(s, 1);  s += __shfl_xor(s, 2);
      s += __shfl_xor(s, 4);  s += __shfl_xor(s, 8);
      int gi = r0 + reg;
      if ((lane & 15) == 0 && gi < SEQ) atomicAdd(&v1[b * SEQ + gi], s);
    }
  }
#pragma unroll
  for (int fj = 0; fj < 4; ++fj) {
    float s = cs[fj];
    s += __shfl_xor(s, 16); s += __shfl_xor(s, 32);
    if (lane < 16 && jv[fj]) atomicAdd(&v2[b * SEQ + gj[fj]], s);
  }
}

// ---------------- width-4 pooling, fp32 x input (fallback path)
__global__ __launch_bounds__(128) void pool_kernel(
    const float* __restrict__ x1, const float* __restrict__ x2,
    const float* __restrict__ v1, const float* __restrict__ v2,
    float* __restrict__ out) {
  const int t     = threadIdx.x;
  const int chunk = blockIdx.x;
  const int b     = blockIdx.y;
  const int which = blockIdx.z;
  const float*  x   = which ? x2 : x1;
  const float*  vec = which ? v2 : v1;
  float4* o = (float4*)out + (size_t)which * ((size_t)BATCH * SOUT * DIM / 4);
  const float4* xr = (const float4*)(x + (size_t)b * SEQ * DIM);
  const float*  vb = vec + b * SEQ;
  const int j0 = chunk * 64;

  float4 r0 = {0,0,0,0}, r1 = {0,0,0,0}, r2 = {0,0,0,0}, r3 = {0,0,0,0};
#pragma unroll 1
  for (int g = 0; g < 17; ++g) {
#pragma unroll
    for (int u = 0; u < 4; ++u) {
      int kk = g * 4 + u;
      int k  = j0 + kk;
      float4 val = {0,0,0,0};
      if (k < SEQ) {
        float  w  = vb[k];
        float4 xv = xr[(size_t)k * 128 + t];
        val.x = w * xv.x; val.y = w * xv.y; val.z = w * xv.z; val.w = w * xv.w;
      }
      if      (u == 0) r0 = val;
      else if (u == 1) r1 = val;
      else if (u == 2) r2 = val;
      else             r3 = val;
      if (kk >= 3 && kk <= 66) {
        int jout = k - 3;
        float4 sum;
        sum.x = r0.x + r1.x + r2.x + r3.x;
        sum.y = r0.y + r1.y + r2.y + r3.y;
        sum.z = r0.z + r1.z + r2.z + r3.z;
        sum.w = r0.w + r1.w + r2.w + r3.w;
        o[((size_t)b * SOUT + jout) * 128 + t] = sum;
      }
    }
  }
}

extern "C" void kernel_launch(void* const* d_in, const int* in_sizes, int n_in,
                              void* d_out, int out_size, void* d_ws, size_t ws_size,
                              hipStream_t stream) {
  const float* x1 = (const float*)d_in[0];
  const float* x2 = (const float*)d_in[1];
  float* out = (float*)d_out;
  float* ws  = (float*)d_ws;
  float* nrm = ws;             // 2*BS_ floats (na | nb)
  float* v1  = ws + 2 * BS_;   // BS_ floats
  float* v2  = ws + 3 * BS_;   // BS_ floats

  const size_t need = (size_t)4 * BS_ * sizeof(float)
                    + (size_t)2 * BS_ * DIM * sizeof(unsigned short);

  if (ws_size >= need) {
    unsigned short* x1b = (unsigned short*)(ws + 4 * BS_);
    unsigned short* x2b = x1b + (size_t)BS_ * DIM;
    convert_norms_kernel<<<(2 * BS_ + 3) / 4, 256, 0, stream>>>(x1, x2, x1b, x2b, nrm);
    gemm_batch_kernel<<<BATCH, 512, 0, stream>>>(x1b, x2b, nrm, v1, v2);
    pool_bf16_kernel<<<dim3(8, BATCH, 2), 128, 0, stream>>>(x1b, x2b, v1, v2, out);
  } else {
    hipMemsetAsync(v1, 0, 2 * (size_t)BS_ * sizeof(float), stream);
    norms_kernel<<<(2 * BS_ + 3) / 4, 256, 0, stream>>>(x1, x2, nrm);
    attn_sums_kernel<<<dim3(NT * NT, BATCH), 256, 0, stream>>>(x1, x2, nrm, v1, v2);
    pool_kernel<<<dim3(8, BATCH, 2), 128, 0, stream>>>(x1, x2, v1, v2, out);
  }
}